// Round 7
// baseline (522.126 us; speedup 1.0000x reference)
//
#include <hip/hip_runtime.h>
#include <hip/hip_bf16.h>

// out[b,s,h] = sum_d x[b,s,d] * W[cat[b],d,h] + bias[cat[b],h]
// Strategy: prepass casts x -> bf16 [B][S][K], W -> bf16 transposed [C][N][K];
// then 128x128 MFMA GEMM with BK=32 double-buffered LDS (32 KB total, same as
// R3) and ONE vmcnt(0)+s_barrier per K-tile placed AFTER the MFMA cluster:
// stage(t+1) issue -> compute(t) -> wait -> barrier. Loads get compute cover.

#define SEQ 512
#define DIN 1024
#define DH  4096
#define NCAT 16
#define NB   64
#define BK   32
#define NKT  (DIN / BK)

typedef __attribute__((ext_vector_type(8))) short   short8;
typedef __attribute__((ext_vector_type(8))) __bf16  bf16x8;
typedef __attribute__((ext_vector_type(4))) __bf16  bf16x4;
typedef __attribute__((ext_vector_type(4))) float   f32x4;

static __device__ __forceinline__ void gload_lds16(const void* g, void* l) {
    __builtin_amdgcn_global_load_lds(
        (const __attribute__((address_space(1))) void*)g,
        (__attribute__((address_space(3))) void*)l,
        16, 0, 0);
}

static __device__ __forceinline__ void bar() {
    asm volatile("" ::: "memory");
    __builtin_amdgcn_s_barrier();
    asm volatile("" ::: "memory");
}

#define MFMA_BF16(a, b, c) __builtin_amdgcn_mfma_f32_16x16x32_bf16((a), (b), (c), 0, 0, 0)

// ---------------- prepass 1: x f32 -> bf16 ----------------
__global__ __launch_bounds__(256)
void conv_x(const float* __restrict__ x, __bf16* __restrict__ xb, int n8) {
    int idx = blockIdx.x * 256 + threadIdx.x;
    const int stride = gridDim.x * 256;
    for (; idx < n8; idx += stride) {
        const f32x4 a = ((const f32x4*)x)[(size_t)idx * 2];
        const f32x4 b = ((const f32x4*)x)[(size_t)idx * 2 + 1];
        bf16x8 h;
        h[0]=(__bf16)a[0]; h[1]=(__bf16)a[1]; h[2]=(__bf16)a[2]; h[3]=(__bf16)a[3];
        h[4]=(__bf16)b[0]; h[5]=(__bf16)b[1]; h[6]=(__bf16)b[2]; h[7]=(__bf16)b[3];
        ((bf16x8*)xb)[idx] = h;
    }
}

// ------- prepass 2: W [C][K][N] f32 -> Wt [C][N][K] bf16 (LDS transpose) -------
__global__ __launch_bounds__(256)
void conv_w(const float* __restrict__ W, __bf16* __restrict__ wt) {
    __shared__ float lt[64][65];
    const int t  = threadIdx.x;
    const int nb = blockIdx.x * 64;
    const int kb = blockIdx.y * 64;
    const int c  = blockIdx.z;
    #pragma unroll
    for (int p = 0; p < 4; p++) {
        const int row = (t >> 4) + p * 16;
        const int col = (t & 15) * 4;
        const f32x4 v = *(const f32x4*)(W + ((size_t)c * DIN + kb + row) * DH + nb + col);
        lt[row][col] = v[0]; lt[row][col+1] = v[1];
        lt[row][col+2] = v[2]; lt[row][col+3] = v[3];
    }
    __syncthreads();
    #pragma unroll
    for (int p = 0; p < 2; p++) {
        const int n  = (t >> 3) + p * 32;
        const int k0 = (t & 7) * 8;
        bf16x8 h;
        #pragma unroll
        for (int j = 0; j < 8; j++) h[j] = (__bf16)lt[k0 + j][n];
        *(bf16x8*)(wt + ((size_t)c * DH + nb + n) * DIN + kb + k0) = h;
    }
}

// ---------- main GEMM: 128x128, BK=32, dbuf, one barrier per K-tile ----------
// LDS layout: [buf][64 rows of 128B]; LDS row r packs m=2r (k0..31) and
// m=2r+1 (k0..31); 16B group g holds source group g ^ (r&7) (both-sides XOR,
// rule #21). Frag read (m, kgroup lg): byte (m>>1)*128 + (((m&1)*4+lg)^((m>>1)&7))*16
// -> 16 lanes hit each bank-group exactly 2x = conflict-free (m136).
__global__ __launch_bounds__(256, 2)
void gemm_bt(const __bf16* __restrict__ xb, const int* __restrict__ cat_ids,
             const __bf16* __restrict__ wt, const float* __restrict__ bias,
             float* __restrict__ out) {
    __shared__ __align__(16) __bf16 lA[2][64 * 64];   // 2 x 8 KB
    __shared__ __align__(16) __bf16 lB[2][64 * 64];   // 2 x 8 KB

    const int t    = threadIdx.x;
    const int lane = t & 63;
    const int w    = t >> 6;
    const int wm   = (w >> 1) * 64;
    const int wn   = (w & 1) * 64;
    const int l15  = lane & 15;
    const int lg   = lane >> 4;

    // Locality-ordered flattened grid + bijective XCD chunking (proven R6:
    // FETCH 540->323 MB). mb fastest, then nb, then bb.
    const unsigned o = blockIdx.x;
    const unsigned s = (o & 7) * (gridDim.x >> 3) + (o >> 3);
    const int bb  = s >> 7;
    const int r   = s & 127;
    const int nb  = (r >> 2) * 128;
    const int mb  = (r & 3) * 128;
    const int c   = cat_ids[bb];

    const __bf16* xp = xb + ((size_t)bb * SEQ + mb) * DIN;
    const __bf16* wp = wt + ((size_t)c * DH + nb) * DIN;

    // staging: 2 chunks/thread/array; chunk ch: LDS row=ch>>3, group=ch&7;
    // inverse-swizzled source: gs = g ^ (row&7) -> m = 2*row + (gs>>2),
    // k-col = (gs&3)*8. Hoisted to running pointers (+= BK per tile).
    const __bf16* aSrc[2];
    const __bf16* bSrc[2];
    int sdst[2];
    #pragma unroll
    for (int L = 0; L < 2; L++) {
        const int ch = L * 256 + t;
        const int rr = ch >> 3;
        const int gs = (ch & 7) ^ (rr & 7);
        const int ms = 2 * rr + (gs >> 2);
        const int kc = (gs & 3) * 8;
        aSrc[L] = xp + (size_t)ms * DIN + kc;
        bSrc[L] = wp + (size_t)ms * DIN + kc;
        sdst[L] = ch * 8;
    }
    auto stage = [&](int buf, int j) {
        const int ko = j * BK;
        #pragma unroll
        for (int L = 0; L < 2; L++) {
            gload_lds16(aSrc[L] + ko, &lA[buf][sdst[L]]);
            gload_lds16(bSrc[L] + ko, &lB[buf][sdst[L]]);
        }
    };
    auto rdfrag = [&](const __bf16* slot, int row) -> short8 {
        const int g = ((row & 1) * 4 + lg) ^ ((row >> 1) & 7);
        return *(const short8*)((const char*)slot + ((row >> 1) * 128 + g * 16));
    };

    f32x4 acc[4][4];
    #pragma unroll
    for (int i = 0; i < 4; i++)
        #pragma unroll
        for (int j = 0; j < 4; j++) acc[i][j] = (f32x4)0.f;

    // prologue: tile 0 into buf 0, drain, publish
    stage(0, 0);
    asm volatile("s_waitcnt vmcnt(0)" ::: "memory");
    bar();

    for (int j = 0; j < NKT; ++j) {
        const int cur = j & 1;
        if (j + 1 < NKT) stage(cur ^ 1, j + 1);   // issue FIRST (cover = compute)

        short8 bfv[4];
        #pragma unroll
        for (int fn = 0; fn < 4; fn++)
            bfv[fn] = rdfrag(&lB[cur][0], wn + fn * 16 + l15);
        #pragma unroll
        for (int fm = 0; fm < 4; fm++) {
            const short8 af = rdfrag(&lA[cur][0], wm + fm * 16 + l15);
            #pragma unroll
            for (int fn = 0; fn < 4; fn++)
                acc[fm][fn] = MFMA_BF16(af, bfv[fn], acc[fm][fn]);
        }

        asm volatile("s_waitcnt vmcnt(0)" ::: "memory");  // AFTER compute
        bar();   // reads of cur done + all stages visible
    }

    const float* bp = bias + (size_t)c * DH;
    float*       op = out + (size_t)bb * SEQ * DH;
    #pragma unroll
    for (int fn = 0; fn < 4; fn++) {
        const int col = nb + wn + fn * 16 + l15;
        const float bv = bp[col];
        #pragma unroll
        for (int fm = 0; fm < 4; fm++) {
            const int row0 = mb + wm + fm * 16 + lg * 4;
            #pragma unroll
            for (int r2 = 0; r2 < 4; r2++)
                op[(size_t)(row0 + r2) * DH + col] = acc[fm][fn][r2] + bv;
        }
    }
}

// ---------------- fallback (ws too small): fused 128x128 ----------------
static __device__ __forceinline__ int swz_fb(int row) {
    return ((row ^ (row >> 3)) & 7) << 4;
}
__global__ __launch_bounds__(256, 2)
void cat_lin_fb(const float* __restrict__ x, const int* __restrict__ cat_ids,
                const float* __restrict__ W, const float* __restrict__ bias,
                float* __restrict__ out) {
    __shared__ unsigned char lAf[128 * 64 * 2];
    __shared__ unsigned char lBf[128 * 64 * 2];
    const int t = threadIdx.x, lane = t & 63, wave = t >> 6;
    const int wm = (wave >> 1) * 64, wn = (wave & 1) * 64;
    const int l15 = lane & 15, lg = lane >> 4;
    const int nb = blockIdx.x * 128, mb = blockIdx.y * 128, bb = blockIdx.z;
    const int c = cat_ids[bb];
    const float* xp = x + (size_t)bb * SEQ * DIN + (size_t)mb * DIN;
    const float* wp = W + (size_t)c * DIN * DH + nb;
    f32x4 acc[4][4];
    #pragma unroll
    for (int i = 0; i < 4; i++)
        #pragma unroll
        for (int j = 0; j < 4; j++) acc[i][j] = (f32x4)0.f;
    const int aM = t >> 4, aK = (t & 15) * 4;
    const int bN = (t & 31) * 4, bK = (t >> 5) * 4;
    for (int kt = 0; kt < DIN; kt += 64) {
        #pragma unroll
        for (int i = 0; i < 8; i++) {
            const int m = aM + i * 16;
            const f32x4 v = *(const f32x4*)(xp + (size_t)m * DIN + kt + aK);
            bf16x4 h;
            h[0]=(__bf16)v[0]; h[1]=(__bf16)v[1]; h[2]=(__bf16)v[2]; h[3]=(__bf16)v[3];
            *(bf16x4*)(&lAf[m * 128 + ((aK * 2) ^ swz_fb(m))]) = h;
        }
        #pragma unroll
        for (int i = 0; i < 2; i++) {
            const int k0 = bK + i * 32;
            const float* wr = wp + (size_t)(kt + k0) * DH + bN;
            const f32x4 r0 = *(const f32x4*)(wr);
            const f32x4 r1 = *(const f32x4*)(wr + DH);
            const f32x4 r2 = *(const f32x4*)(wr + 2 * (size_t)DH);
            const f32x4 r3 = *(const f32x4*)(wr + 3 * (size_t)DH);
            #pragma unroll
            for (int jj = 0; jj < 4; jj++) {
                bf16x4 h;
                h[0]=(__bf16)r0[jj]; h[1]=(__bf16)r1[jj];
                h[2]=(__bf16)r2[jj]; h[3]=(__bf16)r3[jj];
                const int n = bN + jj;
                *(bf16x4*)(&lBf[n * 128 + ((k0 * 2) ^ swz_fb(n))]) = h;
            }
        }
        __syncthreads();
        #pragma unroll
        for (int ks = 0; ks < 2; ks++) {
            const int kb2 = ks * 64 + lg * 16;
            short8 bfv[4];
            #pragma unroll
            for (int fn = 0; fn < 4; fn++) {
                const int n = wn + fn * 16 + l15;
                bfv[fn] = *(const short8*)(&lBf[n * 128 + (kb2 ^ swz_fb(n))]);
            }
            #pragma unroll
            for (int fm = 0; fm < 4; fm++) {
                const int m = wm + fm * 16 + l15;
                const short8 af = *(const short8*)(&lAf[m * 128 + (kb2 ^ swz_fb(m))]);
                #pragma unroll
                for (int fn = 0; fn < 4; fn++)
                    acc[fm][fn] = MFMA_BF16(af, bfv[fn], acc[fm][fn]);
            }
        }
        __syncthreads();
    }
    const float* bp = bias + (size_t)c * DH;
    float* op = out + (size_t)bb * SEQ * DH;
    #pragma unroll
    for (int fn = 0; fn < 4; fn++) {
        const int col = nb + wn + fn * 16 + l15;
        const float bv = bp[col];
        #pragma unroll
        for (int fm = 0; fm < 4; fm++) {
            const int row0 = mb + wm + fm * 16 + lg * 4;
            #pragma unroll
            for (int r = 0; r < 4; r++)
                op[(size_t)(row0 + r) * DH + col] = acc[fm][fn][r] + bv;
        }
    }
}

extern "C" void kernel_launch(void* const* d_in, const int* in_sizes, int n_in,
                              void* d_out, int out_size, void* d_ws, size_t ws_size,
                              hipStream_t stream) {
    const float* x   = (const float*)d_in[0];
    const int*   cid = (const int*)d_in[1];
    const float* W   = (const float*)d_in[2];
    const float* b   = (const float*)d_in[3];
    float*       out = (float*)d_out;

    const size_t xb_bytes = (size_t)NB * SEQ * DIN * 2;
    const size_t wt_bytes = (size_t)NCAT * DH * DIN * 2;

    if (ws_size >= xb_bytes + wt_bytes) {
        __bf16* xbuf = (__bf16*)d_ws;
        __bf16* wbuf = (__bf16*)((char*)d_ws + xb_bytes);
        conv_x<<<2048, 256, 0, stream>>>(x, xbuf, NB * SEQ * DIN / 8);
        dim3 gw(DH / 64, DIN / 64, NCAT);
        conv_w<<<gw, 256, 0, stream>>>(W, wbuf);
        gemm_bt<<<dim3(NB * (DH / 128) * (SEQ / 128)), dim3(256), 0, stream>>>(
            xbuf, cid, wbuf, b, out);
    } else {
        dim3 gg(DH / 128, SEQ / 128, NB);
        cat_lin_fb<<<gg, 256, 0, stream>>>(x, cid, W, b, out);
    }
}

// Round 8
// 514.890 us; speedup vs baseline: 1.0141x; 1.0141x over previous
//
#include <hip/hip_runtime.h>
#include <hip/hip_bf16.h>

// out[b,s,h] = sum_d x[b,s,d] * W[cat[b],d,h] + bias[cat[b],h]
// Strategy: one fused prepass dispatch casts x -> bf16 [B][S][K] and
// W -> bf16 transposed [C][N][K] in d_ws; then the R3-proven 128x128
// 2-barrier MFMA GEMM (global_load_lds + both-sides XOR swizzle, R6 locality
// grid), K-loop fully unrolled with invariant addresses (imm-offset folding).

#define SEQ 512
#define DIN 1024
#define DH  4096
#define NCAT 16
#define NB   64
#define BK   64
#define NKT  (DIN / BK)

typedef __attribute__((ext_vector_type(8))) short   short8;
typedef __attribute__((ext_vector_type(8))) __bf16  bf16x8;
typedef __attribute__((ext_vector_type(4))) __bf16  bf16x4;
typedef __attribute__((ext_vector_type(4))) float   f32x4;

static __device__ __forceinline__ void gload_lds16(const void* g, void* l) {
    __builtin_amdgcn_global_load_lds(
        (const __attribute__((address_space(1))) void*)g,
        (__attribute__((address_space(3))) void*)l,
        16, 0, 0);
}

#define MFMA_BF16(a, b, c) __builtin_amdgcn_mfma_f32_16x16x32_bf16((a), (b), (c), 0, 0, 0)

// -------- fused prepass: blocks [0, WBLK) transpose W, rest cast x --------
#define WBLK (16384)   // (DH/64) * (DIN/64) * NCAT = 64*16*16
#define XBLK (2048)

__global__ __launch_bounds__(256)
void conv_all(const float* __restrict__ x, __bf16* __restrict__ xb,
              const float* __restrict__ W, __bf16* __restrict__ wt) {
    const int t = threadIdx.x;
    if (blockIdx.x < WBLK) {
        // W [C][K][N] f32 -> Wt [C][N][K] bf16, 64x64 tile via padded LDS
        __shared__ float lt[64][65];
        const unsigned wb = blockIdx.x;
        const int nb = (wb & 63) * 64;
        const int kb = ((wb >> 6) & 15) * 64;
        const int c  = wb >> 10;
        #pragma unroll
        for (int p = 0; p < 4; p++) {
            const int row = (t >> 4) + p * 16;
            const int col = (t & 15) * 4;
            const f32x4 v = *(const f32x4*)(W + ((size_t)c * DIN + kb + row) * DH + nb + col);
            lt[row][col] = v[0]; lt[row][col+1] = v[1];
            lt[row][col+2] = v[2]; lt[row][col+3] = v[3];
        }
        __syncthreads();
        #pragma unroll
        for (int p = 0; p < 2; p++) {
            const int n  = (t >> 3) + p * 32;
            const int k0 = (t & 7) * 8;
            bf16x8 h;
            #pragma unroll
            for (int j = 0; j < 8; j++) h[j] = (__bf16)lt[k0 + j][n];
            *(bf16x8*)(wt + ((size_t)c * DH + nb + n) * DIN + kb + k0) = h;
        }
    } else {
        // x f32 -> bf16 flat cast, grid-stride
        const int n8 = NB * SEQ * DIN / 8;
        int idx = (blockIdx.x - WBLK) * 256 + t;
        for (; idx < n8; idx += XBLK * 256) {
            const f32x4 a = ((const f32x4*)x)[(size_t)idx * 2];
            const f32x4 b = ((const f32x4*)x)[(size_t)idx * 2 + 1];
            bf16x8 h;
            h[0]=(__bf16)a[0]; h[1]=(__bf16)a[1]; h[2]=(__bf16)a[2]; h[3]=(__bf16)a[3];
            h[4]=(__bf16)b[0]; h[5]=(__bf16)b[1]; h[6]=(__bf16)b[2]; h[7]=(__bf16)b[3];
            ((bf16x8*)xb)[idx] = h;
        }
    }
}

// ---------------- main GEMM: R3 core, fully unrolled K-loop ----------------
// LDS slot (row, g) holds source group g ^ (row&7) (g = 16B group, 8/row);
// staged via inverse-permuted GLOBAL address, read with same XOR.
// Verified R3/R6: 0 bank conflicts.
__global__ __launch_bounds__(256, 2)
void gemm_bt(const __bf16* __restrict__ xb, const int* __restrict__ cat_ids,
             const __bf16* __restrict__ wt, const float* __restrict__ bias,
             float* __restrict__ out) {
    __shared__ __align__(16) __bf16 lA[128 * 64];   // 16 KB
    __shared__ __align__(16) __bf16 lB[128 * 64];   // 16 KB

    const int t    = threadIdx.x;
    const int lane = t & 63;
    const int w    = t >> 6;
    const int wm   = (w >> 1) * 64;
    const int wn   = (w & 1) * 64;
    const int l15  = lane & 15;
    const int lg   = lane >> 4;

    // Locality-ordered flattened grid + bijective XCD chunking (proven R6:
    // FETCH 540->323 MB). mb fastest, then nb, then bb.
    const unsigned o = blockIdx.x;
    const unsigned s = (o & 7) * (gridDim.x >> 3) + (o >> 3);
    const int bb  = s >> 7;
    const int r   = s & 127;
    const int nb  = (r >> 2) * 128;
    const int mb  = (r & 3) * 128;
    const int c   = cat_ids[bb];

    const __bf16* xp = xb + ((size_t)bb * SEQ + mb) * DIN;
    const __bf16* wp = wt + ((size_t)c * DH + nb) * DIN;

    // ---- staging sources (loop-invariant): chunk q = w*4+i covers rows
    // q*8..q*8+7; lane>>3 = row&7; inverse-swizzled source column group.
    const int srow = lane >> 3;
    const int scol = ((lane & 7) ^ (lane >> 3)) * 8;
    const __bf16* aS[4]; const __bf16* bS[4];
    __bf16* dA[4]; __bf16* dB[4];
    #pragma unroll
    for (int i = 0; i < 4; i++) {
        const int q  = w * 4 + i;
        const int rr = q * 8 + srow;
        aS[i] = xp + (size_t)rr * DIN + scol;
        bS[i] = wp + (size_t)rr * DIN + scol;
        dA[i] = &lA[q * 512];
        dB[i] = &lB[q * 512];
    }

    // ---- fragment read addresses (loop-invariant): byte =
    // row*128 + ((ks*64 + lg*16) ^ ((row&7)<<4)); row&7 == l15&7.
    const int swzb = (l15 & 7) << 4;
    const char* aRd[2], * bRd[2];
    #pragma unroll
    for (int ks = 0; ks < 2; ks++) {
        const int kk = (ks * 64 + lg * 16) ^ swzb;
        aRd[ks] = (const char*)lA + (wm + l15) * 128 + kk;
        bRd[ks] = (const char*)lB + (wn + l15) * 128 + kk;
    }

    f32x4 acc[4][4];
    #pragma unroll
    for (int i = 0; i < 4; i++)
        #pragma unroll
        for (int j = 0; j < 4; j++) acc[i][j] = (f32x4)0.f;

    #pragma unroll
    for (int j = 0; j < NKT; ++j) {
        const int ko = j * BK;                 // constant per unrolled copy
        #pragma unroll
        for (int i = 0; i < 4; i++) {
            gload_lds16(aS[i] + ko, dA[i]);    // ko*2 bytes folds into imm
            gload_lds16(bS[i] + ko, dB[i]);
        }
        __syncthreads();                       // stages resident + visible

        #pragma unroll
        for (int ks = 0; ks < 2; ks++) {
            short8 bfv[4];
            #pragma unroll
            for (int fn = 0; fn < 4; fn++)
                bfv[fn] = *(const short8*)(bRd[ks] + fn * 2048);  // imm offset
            #pragma unroll
            for (int fm = 0; fm < 4; fm++) {
                const short8 af = *(const short8*)(aRd[ks] + fm * 2048);
                #pragma unroll
                for (int fn = 0; fn < 4; fn++)
                    acc[fm][fn] = MFMA_BF16(af, bfv[fn], acc[fm][fn]);
            }
        }
        __syncthreads();                       // reads done before overwrite
    }

    // epilogue: D[row = lg*4 + r][col = l15] per 16x16 frag (verified R1/R3)
    const float* bp = bias + (size_t)c * DH;
    float*       op = out + (size_t)bb * SEQ * DH;
    #pragma unroll
    for (int fn = 0; fn < 4; fn++) {
        const int col = nb + wn + fn * 16 + l15;
        const float bv = bp[col];
        #pragma unroll
        for (int fm = 0; fm < 4; fm++) {
            const int row0 = mb + wm + fm * 16 + lg * 4;
            #pragma unroll
            for (int r2 = 0; r2 < 4; r2++)
                op[(size_t)(row0 + r2) * DH + col] = acc[fm][fn][r2] + bv;
        }
    }
}

// ---------------- fallback (ws too small): fused 128x128 ----------------
static __device__ __forceinline__ int swz_fb(int row) {
    return ((row ^ (row >> 3)) & 7) << 4;
}
__global__ __launch_bounds__(256, 2)
void cat_lin_fb(const float* __restrict__ x, const int* __restrict__ cat_ids,
                const float* __restrict__ W, const float* __restrict__ bias,
                float* __restrict__ out) {
    __shared__ unsigned char lAf[128 * 64 * 2];
    __shared__ unsigned char lBf[128 * 64 * 2];
    const int t = threadIdx.x, lane = t & 63, wave = t >> 6;
    const int wm = (wave >> 1) * 64, wn = (wave & 1) * 64;
    const int l15 = lane & 15, lg = lane >> 4;
    const int nb = blockIdx.x * 128, mb = blockIdx.y * 128, bb = blockIdx.z;
    const int c = cat_ids[bb];
    const float* xp = x + (size_t)bb * SEQ * DIN + (size_t)mb * DIN;
    const float* wp = W + (size_t)c * DIN * DH + nb;
    f32x4 acc[4][4];
    #pragma unroll
    for (int i = 0; i < 4; i++)
        #pragma unroll
        for (int j = 0; j < 4; j++) acc[i][j] = (f32x4)0.f;
    const int aM = t >> 4, aK = (t & 15) * 4;
    const int bN = (t & 31) * 4, bK = (t >> 5) * 4;
    for (int kt = 0; kt < DIN; kt += 64) {
        #pragma unroll
        for (int i = 0; i < 8; i++) {
            const int m = aM + i * 16;
            const f32x4 v = *(const f32x4*)(xp + (size_t)m * DIN + kt + aK);
            bf16x4 h;
            h[0]=(__bf16)v[0]; h[1]=(__bf16)v[1]; h[2]=(__bf16)v[2]; h[3]=(__bf16)v[3];
            *(bf16x4*)(&lAf[m * 128 + ((aK * 2) ^ swz_fb(m))]) = h;
        }
        #pragma unroll
        for (int i = 0; i < 2; i++) {
            const int k0 = bK + i * 32;
            const float* wr = wp + (size_t)(kt + k0) * DH + bN;
            const f32x4 r0 = *(const f32x4*)(wr);
            const f32x4 r1 = *(const f32x4*)(wr + DH);
            const f32x4 r2 = *(const f32x4*)(wr + 2 * (size_t)DH);
            const f32x4 r3 = *(const f32x4*)(wr + 3 * (size_t)DH);
            #pragma unroll
            for (int jj = 0; jj < 4; jj++) {
                bf16x4 h;
                h[0]=(__bf16)r0[jj]; h[1]=(__bf16)r1[jj];
                h[2]=(__bf16)r2[jj]; h[3]=(__bf16)r3[jj];
                const int n = bN + jj;
                *(bf16x4*)(&lBf[n * 128 + ((k0 * 2) ^ swz_fb(n))]) = h;
            }
        }
        __syncthreads();
        #pragma unroll
        for (int ks = 0; ks < 2; ks++) {
            const int kb2 = ks * 64 + lg * 16;
            short8 bfv[4];
            #pragma unroll
            for (int fn = 0; fn < 4; fn++) {
                const int n = wn + fn * 16 + l15;
                bfv[fn] = *(const short8*)(&lBf[n * 128 + (kb2 ^ swz_fb(n))]);
            }
            #pragma unroll
            for (int fm = 0; fm < 4; fm++) {
                const int m = wm + fm * 16 + l15;
                const short8 af = *(const short8*)(&lAf[m * 128 + (kb2 ^ swz_fb(m))]);
                #pragma unroll
                for (int fn = 0; fn < 4; fn++)
                    acc[fm][fn] = MFMA_BF16(af, bfv[fn], acc[fm][fn]);
            }
        }
        __syncthreads();
    }
    const float* bp = bias + (size_t)c * DH;
    float* op = out + (size_t)bb * SEQ * DH;
    #pragma unroll
    for (int fn = 0; fn < 4; fn++) {
        const int col = nb + wn + fn * 16 + l15;
        const float bv = bp[col];
        #pragma unroll
        for (int fm = 0; fm < 4; fm++) {
            const int row0 = mb + wm + fm * 16 + lg * 4;
            #pragma unroll
            for (int r = 0; r < 4; r++)
                op[(size_t)(row0 + r) * DH + col] = acc[fm][fn][r] + bv;
        }
    }
}

extern "C" void kernel_launch(void* const* d_in, const int* in_sizes, int n_in,
                              void* d_out, int out_size, void* d_ws, size_t ws_size,
                              hipStream_t stream) {
    const float* x   = (const float*)d_in[0];
    const int*   cid = (const int*)d_in[1];
    const float* W   = (const float*)d_in[2];
    const float* b   = (const float*)d_in[3];
    float*       out = (float*)d_out;

    const size_t xb_bytes = (size_t)NB * SEQ * DIN * 2;
    const size_t wt_bytes = (size_t)NCAT * DH * DIN * 2;

    if (ws_size >= xb_bytes + wt_bytes) {
        __bf16* xbuf = (__bf16*)d_ws;
        __bf16* wbuf = (__bf16*)((char*)d_ws + xb_bytes);
        conv_all<<<dim3(WBLK + XBLK), dim3(256), 0, stream>>>(x, xbuf, W, wbuf);
        gemm_bt<<<dim3(NB * (DH / 128) * (SEQ / 128)), dim3(256), 0, stream>>>(
            xbuf, cid, wbuf, b, out);
    } else {
        dim3 gg(DH / 128, SEQ / 128, NB);
        cat_lin_fb<<<gg, 256, 0, stream>>>(x, cid, W, b, out);
    }
}

// Round 9
// 486.222 us; speedup vs baseline: 1.0738x; 1.0590x over previous
//
#include <hip/hip_runtime.h>
#include <hip/hip_bf16.h>

// out[b,s,h] = sum_d x[b,s,d] * W[cat[b],d,h] + bias[cat[b],h]
// Strategy: fused prepass casts x -> bf16 [B][S][K] and W -> bf16 transposed
// [C][N][K] in d_ws; tiny kernel counting-sorts batches by category into
// perm[]; then the R6-proven 128x128 2-barrier MFMA GEMM (global_load_lds +
// both-sides XOR swizzle) with expert-grouped, XCD-chunked grid mapping.

#define SEQ 512
#define DIN 1024
#define DH  4096
#define NCAT 16
#define NB   64
#define BK   64

typedef __attribute__((ext_vector_type(8))) short   short8;
typedef __attribute__((ext_vector_type(8))) __bf16  bf16x8;
typedef __attribute__((ext_vector_type(4))) __bf16  bf16x4;
typedef __attribute__((ext_vector_type(4))) float   f32x4;

static __device__ __forceinline__ void gload_lds16(const void* g, void* l) {
    __builtin_amdgcn_global_load_lds(
        (const __attribute__((address_space(1))) void*)g,
        (__attribute__((address_space(3))) void*)l,
        16, 0, 0);
}

#define MFMA_BF16(a, b, c) __builtin_amdgcn_mfma_f32_16x16x32_bf16((a), (b), (c), 0, 0, 0)

// -------- fused prepass: blocks [0, WBLK) transpose W, rest cast x --------
#define WBLK (16384)   // (DH/64) * (DIN/64) * NCAT
#define XBLK (2048)

__global__ __launch_bounds__(256)
void conv_all(const float* __restrict__ x, __bf16* __restrict__ xb,
              const float* __restrict__ W, __bf16* __restrict__ wt) {
    const int t = threadIdx.x;
    if (blockIdx.x < WBLK) {
        __shared__ float lt[64][65];
        const unsigned wb = blockIdx.x;
        const int nb = (wb & 63) * 64;
        const int kb = ((wb >> 6) & 15) * 64;
        const int c  = wb >> 10;
        #pragma unroll
        for (int p = 0; p < 4; p++) {
            const int row = (t >> 4) + p * 16;
            const int col = (t & 15) * 4;
            const f32x4 v = *(const f32x4*)(W + ((size_t)c * DIN + kb + row) * DH + nb + col);
            lt[row][col] = v[0]; lt[row][col+1] = v[1];
            lt[row][col+2] = v[2]; lt[row][col+3] = v[3];
        }
        __syncthreads();
        #pragma unroll
        for (int p = 0; p < 2; p++) {
            const int n  = (t >> 3) + p * 32;
            const int k0 = (t & 7) * 8;
            bf16x8 h;
            #pragma unroll
            for (int j = 0; j < 8; j++) h[j] = (__bf16)lt[k0 + j][n];
            *(bf16x8*)(wt + ((size_t)c * DH + nb + n) * DIN + kb + k0) = h;
        }
    } else {
        const int n8 = NB * SEQ * DIN / 8;
        int idx = (blockIdx.x - WBLK) * 256 + t;
        for (; idx < n8; idx += XBLK * 256) {
            const f32x4 a = ((const f32x4*)x)[(size_t)idx * 2];
            const f32x4 b = ((const f32x4*)x)[(size_t)idx * 2 + 1];
            bf16x8 h;
            h[0]=(__bf16)a[0]; h[1]=(__bf16)a[1]; h[2]=(__bf16)a[2]; h[3]=(__bf16)a[3];
            h[4]=(__bf16)b[0]; h[5]=(__bf16)b[1]; h[6]=(__bf16)b[2]; h[7]=(__bf16)b[3];
            ((bf16x8*)xb)[idx] = h;
        }
    }
}

// -------- batch permutation: stable counting sort by category --------
// Groups same-expert batches into contiguous grid chunks so each XCD's
// L2 sees ~2 experts instead of ~7 (cuts W panel re-fetch).
__global__ void sort_batches(const int* __restrict__ cat, int* __restrict__ perm) {
    if (threadIdx.x == 0) {
        int cnt[NCAT];
        #pragma unroll
        for (int c = 0; c < NCAT; c++) cnt[c] = 0;
        for (int i = 0; i < NB; i++) cnt[cat[i]]++;
        int off[NCAT]; int s = 0;
        #pragma unroll
        for (int c = 0; c < NCAT; c++) { off[c] = s; s += cnt[c]; }
        for (int i = 0; i < NB; i++) perm[off[cat[i]]++] = i;
    }
}

// ---------------- main GEMM: R6-proven 128x128, BK=64, 4 waves ----------------
// LDS slot (row, g) holds source group g ^ (row&7) (g = 16B group, 8/row);
// staged via inverse-permuted GLOBAL address, read with same XOR.
// Verified R3/R6: 0 bank conflicts, VGPR 64, 370 us.
__global__ __launch_bounds__(256, 2)
void gemm_bt(const __bf16* __restrict__ xb, const int* __restrict__ cat_ids,
             const __bf16* __restrict__ wt, const float* __restrict__ bias,
             const int* __restrict__ perm, float* __restrict__ out) {
    __shared__ __align__(16) __bf16 lA[128 * 64];   // 16 KB
    __shared__ __align__(16) __bf16 lB[128 * 64];   // 16 KB

    const int t    = threadIdx.x;
    const int lane = t & 63;
    const int w    = t >> 6;
    const int wm   = (w >> 1) * 64;
    const int wn   = (w & 1) * 64;
    const int l15  = lane & 15;
    const int lg   = lane >> 4;

    // Expert-grouped, locality-ordered grid + bijective XCD chunking.
    // mb fastest (W-panel reuse x4), then nb sweep, then perm-ordered batch.
    const unsigned o = blockIdx.x;
    const unsigned s = (o & 7) * (gridDim.x >> 3) + (o >> 3);
    const int bb  = perm[s >> 7];
    const int r   = s & 127;
    const int nb  = (r >> 2) * 128;
    const int mb  = (r & 3) * 128;
    const int c   = cat_ids[bb];

    const __bf16* xp = xb + ((size_t)bb * SEQ + mb) * DIN;
    const __bf16* wp = wt + ((size_t)c * DH + nb) * DIN;

    const int srow = lane >> 3;
    const int scol = ((lane & 7) ^ (lane >> 3)) * 8;

    f32x4 acc[4][4];
    #pragma unroll
    for (int i = 0; i < 4; i++)
        #pragma unroll
        for (int j = 0; j < 4; j++) acc[i][j] = (f32x4)0.f;

    for (int kt = 0; kt < DIN; kt += 64) {
        #pragma unroll
        for (int i = 0; i < 4; i++) {
            const int q = w * 4 + i;
            const int rr = q * 8 + srow;
            gload_lds16(xp + (size_t)rr * DIN + kt + scol, &lA[q * 512]);
            gload_lds16(wp + (size_t)rr * DIN + kt + scol, &lB[q * 512]);
        }
        __syncthreads();   // drains vmcnt(0): tiles resident + visible

        #pragma unroll
        for (int ks = 0; ks < 2; ks++) {
            const int kob = (ks * 32 + lg * 8) * 2;
            short8 bfv[4];
            #pragma unroll
            for (int fn = 0; fn < 4; fn++) {
                const int n = wn + fn * 16 + l15;
                bfv[fn] = *(const short8*)((const char*)lB +
                            (n * 128 + (kob ^ ((n & 7) << 4))));
            }
            #pragma unroll
            for (int fm = 0; fm < 4; fm++) {
                const int m = wm + fm * 16 + l15;
                const short8 af = *(const short8*)((const char*)lA +
                            (m * 128 + (kob ^ ((m & 7) << 4))));
                #pragma unroll
                for (int fn = 0; fn < 4; fn++)
                    acc[fm][fn] = MFMA_BF16(af, bfv[fn], acc[fm][fn]);
            }
        }
        __syncthreads();   // reads done before next stage overwrites
    }

    const float* bp = bias + (size_t)c * DH;
    float*       op = out + (size_t)bb * SEQ * DH;
    #pragma unroll
    for (int fn = 0; fn < 4; fn++) {
        const int col = nb + wn + fn * 16 + l15;
        const float bv = bp[col];
        #pragma unroll
        for (int fm = 0; fm < 4; fm++) {
            const int row0 = mb + wm + fm * 16 + lg * 4;
            #pragma unroll
            for (int r2 = 0; r2 < 4; r2++)
                op[(size_t)(row0 + r2) * DH + col] = acc[fm][fn][r2] + bv;
        }
    }
}

// ---------------- fallback (ws too small): fused 128x128 ----------------
static __device__ __forceinline__ int swz_fb(int row) {
    return ((row ^ (row >> 3)) & 7) << 4;
}
__global__ __launch_bounds__(256, 2)
void cat_lin_fb(const float* __restrict__ x, const int* __restrict__ cat_ids,
                const float* __restrict__ W, const float* __restrict__ bias,
                float* __restrict__ out) {
    __shared__ unsigned char lAf[128 * 64 * 2];
    __shared__ unsigned char lBf[128 * 64 * 2];
    const int t = threadIdx.x, lane = t & 63, wave = t >> 6;
    const int wm = (wave >> 1) * 64, wn = (wave & 1) * 64;
    const int l15 = lane & 15, lg = lane >> 4;
    const int nb = blockIdx.x * 128, mb = blockIdx.y * 128, bb = blockIdx.z;
    const int c = cat_ids[bb];
    const float* xp = x + (size_t)bb * SEQ * DIN + (size_t)mb * DIN;
    const float* wp = W + (size_t)c * DIN * DH + nb;
    f32x4 acc[4][4];
    #pragma unroll
    for (int i = 0; i < 4; i++)
        #pragma unroll
        for (int j = 0; j < 4; j++) acc[i][j] = (f32x4)0.f;
    const int aM = t >> 4, aK = (t & 15) * 4;
    const int bN = (t & 31) * 4, bK = (t >> 5) * 4;
    for (int kt = 0; kt < DIN; kt += 64) {
        #pragma unroll
        for (int i = 0; i < 8; i++) {
            const int m = aM + i * 16;
            const f32x4 v = *(const f32x4*)(xp + (size_t)m * DIN + kt + aK);
            bf16x4 h;
            h[0]=(__bf16)v[0]; h[1]=(__bf16)v[1]; h[2]=(__bf16)v[2]; h[3]=(__bf16)v[3];
            *(bf16x4*)(&lAf[m * 128 + ((aK * 2) ^ swz_fb(m))]) = h;
        }
        #pragma unroll
        for (int i = 0; i < 2; i++) {
            const int k0 = bK + i * 32;
            const float* wr = wp + (size_t)(kt + k0) * DH + bN;
            const f32x4 r0 = *(const f32x4*)(wr);
            const f32x4 r1 = *(const f32x4*)(wr + DH);
            const f32x4 r2 = *(const f32x4*)(wr + 2 * (size_t)DH);
            const f32x4 r3 = *(const f32x4*)(wr + 3 * (size_t)DH);
            #pragma unroll
            for (int jj = 0; jj < 4; jj++) {
                bf16x4 h;
                h[0]=(__bf16)r0[jj]; h[1]=(__bf16)r1[jj];
                h[2]=(__bf16)r2[jj]; h[3]=(__bf16)r3[jj];
                const int n = bN + jj;
                *(bf16x4*)(&lBf[n * 128 + ((k0 * 2) ^ swz_fb(n))]) = h;
            }
        }
        __syncthreads();
        #pragma unroll
        for (int ks = 0; ks < 2; ks++) {
            const int kb2 = ks * 64 + lg * 16;
            short8 bfv[4];
            #pragma unroll
            for (int fn = 0; fn < 4; fn++) {
                const int n = wn + fn * 16 + l15;
                bfv[fn] = *(const short8*)(&lBf[n * 128 + (kb2 ^ swz_fb(n))]);
            }
            #pragma unroll
            for (int fm = 0; fm < 4; fm++) {
                const int m = wm + fm * 16 + l15;
                const short8 af = *(const short8*)(&lAf[m * 128 + (kb2 ^ swz_fb(m))]);
                #pragma unroll
                for (int fn = 0; fn < 4; fn++)
                    acc[fm][fn] = MFMA_BF16(af, bfv[fn], acc[fm][fn]);
            }
        }
        __syncthreads();
    }
    const float* bp = bias + (size_t)c * DH;
    float* op = out + (size_t)bb * SEQ * DH;
    #pragma unroll
    for (int fn = 0; fn < 4; fn++) {
        const int col = nb + wn + fn * 16 + l15;
        const float bv = bp[col];
        #pragma unroll
        for (int fm = 0; fm < 4; fm++) {
            const int row0 = mb + wm + fm * 16 + lg * 4;
            #pragma unroll
            for (int r = 0; r < 4; r++)
                op[(size_t)(row0 + r) * DH + col] = acc[fm][fn][r] + bv;
        }
    }
}

extern "C" void kernel_launch(void* const* d_in, const int* in_sizes, int n_in,
                              void* d_out, int out_size, void* d_ws, size_t ws_size,
                              hipStream_t stream) {
    const float* x   = (const float*)d_in[0];
    const int*   cid = (const int*)d_in[1];
    const float* W   = (const float*)d_in[2];
    const float* b   = (const float*)d_in[3];
    float*       out = (float*)d_out;

    const size_t xb_bytes = (size_t)NB * SEQ * DIN * 2;
    const size_t wt_bytes = (size_t)NCAT * DH * DIN * 2;

    if (ws_size >= xb_bytes + wt_bytes + 256) {
        __bf16* xbuf = (__bf16*)d_ws;
        __bf16* wbuf = (__bf16*)((char*)d_ws + xb_bytes);
        int*    perm = (int*)((char*)d_ws + xb_bytes + wt_bytes);
        conv_all<<<dim3(WBLK + XBLK), dim3(256), 0, stream>>>(x, xbuf, W, wbuf);
        sort_batches<<<dim3(1), dim3(64), 0, stream>>>(cid, perm);
        gemm_bt<<<dim3(NB * (DH / 128) * (SEQ / 128)), dim3(256), 0, stream>>>(
            xbuf, cid, wbuf, b, perm, out);
    } else {
        dim3 gg(DH / 128, SEQ / 128, NB);
        cat_lin_fb<<<gg, 256, 0, stream>>>(x, cid, W, b, out);
    }
}